// Round 4
// baseline (646.778 us; speedup 1.0000x reference)
//
#include <hip/hip_runtime.h>
#include <math.h>

#define NB 32
#define NC 4
#define NH 512
#define NW 512
#define NT 64
#define NG 2
#define BK 32

typedef __attribute__((ext_vector_type(8))) short short8;
typedef __attribute__((ext_vector_type(4))) float float4v;

__device__ inline unsigned short f2bf(float f) {
  union { float f; unsigned u; } v; v.f = f;
  unsigned r = v.u + 0x7FFF + ((v.u >> 16) & 1);
  return (unsigned short)(r >> 16);
}

// async global->LDS, 16B per lane; dst is wave-uniform base, HW adds lane*16.
// global src IS per-lane.
__device__ __forceinline__ void gld16(const unsigned short* g, unsigned short* l) {
  __builtin_amdgcn_global_load_lds(
      (__attribute__((address_space(1))) const unsigned int*)g,
      (__attribute__((address_space(3))) unsigned int*)l, 16, 0, 0);
}

// ---------------------------------------------------------------------------
// Stage 1 (fused): diff partials AND column-major bf16 transpose Xt.
// Xt[ic*512 + w][ri*512 + h]  (65536 rows x 1024 cols, bf16)
// Block (bg, hc): rows h in [hc*64, hc*64+64) of channels {c0,c1}.
// Thread: q = t&127 -> 4 fixed w's; rg = t>>7 -> 32-h half. Packs 8 h per
// short8 store; 4 stores per (w,arr) fill exactly one 64B line.
// Phase 0: xr[c0] (->Xt[c0] real) with xi[c1] (->Xt[c1] imag): ||r0|-|i1||
// Phase 1: xr[c1] (->Xt[c1] real) with xi[c0] (->Xt[c0] imag): ||r1|-|i0||
// ---------------------------------------------------------------------------
__global__ __launch_bounds__(256) void k_diff_t(const float* __restrict__ xr,
                                                const float* __restrict__ xi,
                                                float* __restrict__ diffp,
                                                unsigned short* __restrict__ Xt) {
  int bg = blockIdx.x, hc = blockIdx.y;
  int b = bg >> 1, g = bg & 1;
  int c0 = b * NC + 2 * g, c1 = c0 + 1;
  int t = threadIdx.x;
  int q = t & 127, rg = t >> 7;
  int h0 = hc * 64 + rg * 32;
  float4v acc = {0.f, 0.f, 0.f, 0.f};

#pragma unroll
  for (int phase = 0; phase < 2; ++phase) {
    const float* PA = (phase ? xr + (size_t)c1 * NH * NW : xr + (size_t)c0 * NH * NW);
    const float* PB = (phase ? xi + (size_t)c0 * NH * NW : xi + (size_t)c1 * NH * NW);
    int icA = phase ? c1 : c0;   // real part dest channel
    int icB = phase ? c0 : c1;   // imag part dest channel
    // dest col base: real -> col h, imag -> col 512 + h
    size_t colA = (size_t)h0;
    size_t colB = (size_t)512 + h0;
#pragma unroll
    for (int i8 = 0; i8 < 4; ++i8) {
      short8 bA[4], bB[4];
#pragma unroll
      for (int u = 0; u < 8; ++u) {
        int h = h0 + i8 * 8 + u;
        float4v a  = *(const float4v*)(PA + (size_t)h * NW + q * 4);
        float4v bb = *(const float4v*)(PB + (size_t)h * NW + q * 4);
#pragma unroll
        for (int k = 0; k < 4; ++k) {
          acc[k] += fabsf(fabsf(a[k]) - fabsf(bb[k]));
          bA[k][u] = (short)f2bf(a[k]);
          bB[k][u] = (short)f2bf(bb[k]);
        }
      }
#pragma unroll
      for (int k = 0; k < 4; ++k) {
        int w = q * 4 + k;
        *(short8*)(Xt + ((size_t)(icA * 512 + w)) * 1024 + colA + i8 * 8) = bA[k];
        *(short8*)(Xt + ((size_t)(icB * 512 + w)) * 1024 + colB + i8 * 8) = bB[k];
      }
    }
  }

  __shared__ float4v red[256];
  red[t] = acc;
  __syncthreads();
  if (t < 128) {
    float4v v = red[t];
    float4v u = red[t + 128];
#pragma unroll
    for (int k = 0; k < 4; ++k) v[k] += u[k];
    *(float4v*)(diffp + ((size_t)hc * 64 + bg) * NW + q * 4) = v;
  }
}

// ---------------------------------------------------------------------------
// Stage 2: sum 8 partials, T smallest per (b,g), stable-argsort rank.
// ---------------------------------------------------------------------------
__global__ void k_select(const float* __restrict__ diffp, int* __restrict__ sel) {
  __shared__ float v[NW];
  int w = threadIdx.x;
  int bg = blockIdx.x;
  float mine = 0.f;
#pragma unroll
  for (int hc = 0; hc < 8; ++hc) mine += diffp[((size_t)hc * 64 + bg) * NW + w];
  v[w] = mine;
  __syncthreads();
  int rank = 0;
  for (int u = 0; u < NW; ++u) {
    float o = v[u];
    rank += (o < mine) || (o == mine && u < w);
  }
  if (rank < NT) sel[bg * NT + rank] = w;
}

// ---------------------------------------------------------------------------
// Build A_big via LDS cos/sin LUT, short8 stores.
// ---------------------------------------------------------------------------
__global__ __launch_bounds__(256) void k_build_T(unsigned short* __restrict__ Tb) {
  __shared__ float2 lt[512];
  int t = threadIdx.x;
  {
    float s, c;
    sincosf(6.2831853071795864769f * (float)t * (1.0f / 512.0f), &s, &c);
    lt[t] = make_float2(c, s);
    sincosf(6.2831853071795864769f * (float)(t + 256) * (1.0f / 512.0f), &s, &c);
    lt[t + 256] = make_float2(c, s);
  }
  __syncthreads();
  int idx0 = (blockIdx.x * 256 + t) * 8;
  int m = idx0 >> 10, k0 = idx0 & 1023;
  int hm = m & 511, rm = m >> 9;
  int rk = k0 >> 9;                       // constant within the 8-group
  short8 o;
#pragma unroll
  for (int u = 0; u < 8; ++u) {
    int hk = (k0 + u) & 511;
    float2 cs = lt[(hm * hk) & 511];
    float val = (rm == rk) ? cs.x : (rk ? -cs.y : cs.y);
    o[u] = (short)f2bf(val * (1.0f / 512.0f));
  }
  *(short8*)(Tb + idx0) = o;
}

// ---------------------------------------------------------------------------
// Build E via LUT, short8 stores, high-occupancy grid (64 bg x 16 chunks)
// ---------------------------------------------------------------------------
__global__ __launch_bounds__(256) void k_build_E(const int* __restrict__ sel,
                                                 unsigned short* __restrict__ Eb) {
  __shared__ int wsel[NT];
  __shared__ float2 lt[512];
  int bg = blockIdx.x;
  int t = threadIdx.x;
  {
    float s, c;
    sincosf(6.2831853071795864769f * (float)t * (1.0f / 512.0f), &s, &c);
    lt[t] = make_float2(c, s);
    sincosf(6.2831853071795864769f * (float)(t + 256) * (1.0f / 512.0f), &s, &c);
    lt[t + 256] = make_float2(c, s);
  }
  if (t < NT) wsel[t] = sel[bg * NT + t];
  __syncthreads();
  int base = blockIdx.y * 8192;
#pragma unroll
  for (int i = 0; i < 4; ++i) {
    int idx0 = base + (i * 256 + t) * 8;    // group of 8 consecutive outputs
    int n = idx0 >> 7, kidx0 = idx0 & 127;
    int j0 = kidx0 & 63, half = kidx0 >> 6; // constant within group
    int part = n >> 9, kk = n & 511;
    short8 o;
#pragma unroll
    for (int u = 0; u < 8; ++u) {
      int w = wsel[j0 + u];
      float2 cs = lt[(kk * w) & 511];
      float val = part == 0 ? (half ? cs.y : cs.x) : (half ? cs.x : -cs.y);
      o[u] = (short)f2bf(val);
    }
    *(short8*)(Eb + (size_t)bg * 131072 + idx0) = o;
  }
}

// ---------------------------------------------------------------------------
// GEMM stage 3: C[1024 x 8192] = T[1024 x 1024] * Xsel^T, where B-rows are
// gathered DIRECTLY from Xt via sel (per-lane global src for gld16; pointer
// per row precomputed once). Double-buffered LDS, one barrier per K-step.
// ---------------------------------------------------------------------------
__global__ __launch_bounds__(256) void k_gemm3(const unsigned short* __restrict__ Tb,
                                               const unsigned short* __restrict__ Xt,
                                               const int* __restrict__ sel,
                                               unsigned short* __restrict__ Yg) {
  __shared__ __align__(16) unsigned short Al[2][128 * BK];
  __shared__ __align__(16) unsigned short Bl[2][128 * BK];
  // bijective chunked XCD swizzle, nwg = 512
  int lin = blockIdx.y * 64 + blockIdx.x;
  int swz = (lin & 7) * 64 + (lin >> 3);
  int n0 = (swz & 63) * 128;
  int m0 = (swz >> 6) * 128;
  int img0 = n0 >> 6;                      // two imgs: img0, img0+1, same (b,g)
  int bg = (img0 >> 2) * 2 + ((img0 >> 1) & 1);
  int tid = threadIdx.x;
  int lane = tid & 63, wid = tid >> 6;
  int wm = wid >> 1, wn = wid & 1;
  int quad = lane >> 4, l15 = lane & 15;
  int srow = lane >> 2, sqd = lane & 3;

  // per-lane source pointers for the two staging chunks (fixed across K)
  const unsigned short* srcA[2];
  const unsigned short* srcB[2];
#pragma unroll
  for (int p = 0; p < 2; ++p) {
    int chunk = wid * 2 + p;
    int row = chunk * 16 + srow;
    int sq = sqd ^ ((row >> 1) & 3);
    srcA[p] = Tb + (size_t)(m0 + row) * 1024 + sq * 8;
    int imgB = img0 + (row >> 6), j = row & 63;
    int w = sel[bg * NT + j];
    srcB[p] = Xt + ((size_t)(imgB * 512 + w)) * 1024 + sq * 8;
  }

  float4v acc[4][4];
#pragma unroll
  for (int i = 0; i < 4; ++i)
#pragma unroll
    for (int j = 0; j < 4; ++j) acc[i][j] = (float4v){0.f, 0.f, 0.f, 0.f};

#define STAGE3(buf, kk0)                                          \
  {                                                               \
    _Pragma("unroll")                                             \
    for (int p = 0; p < 2; ++p) {                                 \
      int chunk = wid * 2 + p;                                    \
      gld16(srcA[p] + (kk0), &Al[buf][chunk * 512]);              \
      gld16(srcB[p] + (kk0), &Bl[buf][chunk * 512]);              \
    }                                                             \
  }

  STAGE3(0, 0);
  __syncthreads();
  int cur = 0;
  for (int t = 0; t < 32; ++t) {
    if (t < 31) STAGE3(cur ^ 1, (t + 1) * 32);

    short8 af[4], bfv[4];
#pragma unroll
    for (int tt = 0; tt < 4; ++tt) {
      int ra = wm * 64 + tt * 16 + l15;
      int rb = wn * 64 + tt * 16 + l15;
      af[tt]  = *(const short8*)&Al[cur][ra * BK + ((quad ^ ((ra >> 1) & 3)) << 3)];
      bfv[tt] = *(const short8*)&Bl[cur][rb * BK + ((quad ^ ((rb >> 1) & 3)) << 3)];
    }
#pragma unroll
    for (int tm = 0; tm < 4; ++tm)
#pragma unroll
      for (int tn = 0; tn < 4; ++tn)
        acc[tm][tn] = __builtin_amdgcn_mfma_f32_16x16x32_bf16(af[tm], bfv[tn], acc[tm][tn], 0, 0, 0);

    __syncthreads();
    cur ^= 1;
  }

  // epilogue: C[m,n] -> Yg[(n>>6)][m&511][(m>>9)*64 + (n&63)]
#pragma unroll
  for (int tm = 0; tm < 4; ++tm)
#pragma unroll
    for (int tn = 0; tn < 4; ++tn)
#pragma unroll
      for (int r = 0; r < 4; ++r) {
        int m = m0 + wm * 64 + tm * 16 + quad * 4 + r;
        int n = n0 + wn * 64 + tn * 16 + l15;
        int img = n >> 6, j = n & 63;
        int h = m & 511, ri = m >> 9;
        Yg[((size_t)img * 512 + h) * 128 + ri * 64 + j] = f2bf(acc[tm][tn][r]);
      }
}

// ---------------------------------------------------------------------------
// GEMM stage 4 (batched over bg): whole-K (128) single-stage LDS panel,
// one barrier pair, 64 MFMA/wave unbroken. Chunk-XOR swizzle both sides.
// ---------------------------------------------------------------------------
__global__ __launch_bounds__(256) void k_gemm4(const unsigned short* __restrict__ Yg,
                                               const unsigned short* __restrict__ Eball,
                                               float2* __restrict__ out) {
  __shared__ __align__(16) unsigned short Al[128 * 128];
  __shared__ __align__(16) unsigned short Bl[128 * 128];
  // bijective chunked XCD swizzle, nwg = 4096 -> 8 bg per XCD
  int lin = blockIdx.x + blockIdx.y * 8 + blockIdx.z * 64;
  int swz = (lin & 7) * 512 + (lin >> 3);
  int n0 = (swz & 7) * 64;           // kk base (64 kk -> 128 cols)
  int m0 = ((swz >> 3) & 7) * 128;
  int bg = swz >> 6;
  int b = bg >> 1, g = bg & 1;
  int img0 = b * 4 + 2 * g;
  const unsigned short* Ab = Yg + (size_t)img0 * 512 * 128;
  const unsigned short* Eb = Eball + (size_t)bg * 131072;

  int tid = threadIdx.x;
  int lane = tid & 63, wid = tid >> 6;
  int wm = wid >> 1, wn = wid & 1;
  int quad = lane >> 4, l15 = lane & 15;
  int lrow4 = lane >> 4, cch = lane & 15;

  // stage whole 128x128 panels: 32 gld16 calls each, 8 per wave
#pragma unroll
  for (int c8 = 0; c8 < 8; ++c8) {
    int call = wid * 8 + c8;            // 0..31, wave-uniform
    int row = call * 4 + lrow4;         // LDS row this lane feeds
    int sch = cch ^ (row & 7);          // inverse swizzle on global src
    gld16(&Ab[(size_t)(m0 + row) * 128 + sch * 8], &Al[call * 512]);
    int l = row & 63, wnB = row >> 6;
    int part = l >> 5;
    int grow = part * 512 + n0 + wnB * 32 + (l & 31);
    gld16(&Eb[(size_t)grow * 128 + sch * 8], &Bl[call * 512]);
  }
  __syncthreads();

  float4v acc[4][4];
#pragma unroll
  for (int i = 0; i < 4; ++i)
#pragma unroll
    for (int j = 0; j < 4; ++j) acc[i][j] = (float4v){0.f, 0.f, 0.f, 0.f};

#pragma unroll
  for (int ks = 0; ks < 4; ++ks) {
    short8 af[4], bfv[4];
#pragma unroll
    for (int tt = 0; tt < 4; ++tt) {
      int ra = wm * 64 + tt * 16 + l15;
      int rb = wn * 64 + tt * 16 + l15;
      af[tt]  = *(const short8*)&Al[ra * 128 + (((ks * 4 + quad) ^ (ra & 7)) << 3)];
      bfv[tt] = *(const short8*)&Bl[rb * 128 + (((ks * 4 + quad) ^ (rb & 7)) << 3)];
    }
#pragma unroll
    for (int tm = 0; tm < 4; ++tm)
#pragma unroll
      for (int tn = 0; tn < 4; ++tn)
        acc[tm][tn] = __builtin_amdgcn_mfma_f32_16x16x32_bf16(af[tm], bfv[tn], acc[tm][tn], 0, 0, 0);
  }

  // epilogue: pair real (t2) with imag (t2+2) -> float2 store
#pragma unroll
  for (int tm = 0; tm < 4; ++tm)
#pragma unroll
    for (int t2 = 0; t2 < 2; ++t2)
#pragma unroll
      for (int r = 0; r < 4; ++r) {
        int m = m0 + wm * 64 + tm * 16 + quad * 4 + r;
        int ch = m >> 9, h = m & 511;
        int img = img0 + ch;
        int kk = n0 + wn * 32 + t2 * 16 + l15;
        float2 v = make_float2(acc[tm][t2][r] + 0.5f, acc[tm][t2 + 2][r]);
        out[((size_t)(img * 512 + h)) * 512 + kk] = v;
      }
}

extern "C" void kernel_launch(void* const* d_in, const int* in_sizes, int n_in,
                              void* d_out, int out_size, void* d_ws, size_t ws_size,
                              hipStream_t stream) {
  const float* xr = (const float*)d_in[0];
  const float* xi = (const float*)d_in[1];
  float2* out = (float2*)d_out;

  char* ws = (char*)d_ws;
  float*          diffp = (float*)ws;                          // 1 MB
  int*            sel   = (int*)(ws + 1048576);                // 16 KB
  unsigned short* Tb    = (unsigned short*)(ws + 2097152);     // 2 MB
  unsigned short* Eb    = (unsigned short*)(ws + 4194304);     // 16 MB
  unsigned short* Yg    = (unsigned short*)(ws + 20971520);    // 16 MB
  unsigned short* Xt    = (unsigned short*)(ws + 37748736);    // 128 MB

  k_diff_t <<<dim3(NB * NG, 8), 256, 0, stream>>>(xr, xi, diffp, Xt);
  k_select <<<NB * NG,          NW, 0, stream>>>(diffp, sel);
  k_build_T<<<512,              256, 0, stream>>>(Tb);
  k_build_E<<<dim3(NB * NG, 16),256, 0, stream>>>(sel, Eb);
  k_gemm3  <<<dim3(64, 8),      256, 0, stream>>>(Tb, Xt, sel, Yg);
  k_gemm4  <<<dim3(8, 8, 64),   256, 0, stream>>>(Yg, Eb, out);
}

// Round 5
// 572.004 us; speedup vs baseline: 1.1307x; 1.1307x over previous
//
#include <hip/hip_runtime.h>
#include <math.h>

#define NB 32
#define NC 4
#define NH 512
#define NW 512
#define NT 64
#define NG 2
#define BK 32

typedef __attribute__((ext_vector_type(8))) short short8;
typedef __attribute__((ext_vector_type(4))) float float4v;

__device__ inline unsigned short f2bf(float f) {
  union { float f; unsigned u; } v; v.f = f;
  unsigned r = v.u + 0x7FFF + ((v.u >> 16) & 1);
  return (unsigned short)(r >> 16);
}

// async global->LDS, 16B per lane; dst is wave-uniform base, HW adds lane*16.
// global src IS per-lane.
__device__ __forceinline__ void gld16(const unsigned short* g, unsigned short* l) {
  __builtin_amdgcn_global_load_lds(
      (__attribute__((address_space(1))) const unsigned int*)g,
      (__attribute__((address_space(3))) unsigned int*)l, 16, 0, 0);
}

// ---------------------------------------------------------------------------
// Stage 1 (fused): diff partials AND column-major bf16 transpose Xt,
// transpose routed through LDS so global stores are full-line coalesced.
// Xt[ic*512 + w][part*512 + h]  (65536 rows x 1024 cols, bf16)
// Block (bg, hc): h in [hc*64, hc*64+64), all 512 w, channels {c0,c1}.
// Per phase / per 32-h subtile: threads (q = t&127 -> 4 w's, rg = t>>7 ->
// 16-h half) pack short8 (8 h) into LDS tiles [512][40] (pad->16B-aligned
// 80B rows; chunk-XOR (w>>2)&3 swizzle -> ~2-way LDS conflicts = free).
// Store-out: lanes 0-3 cover the four 16B chunks of one w row -> each wave
// store = 16 full 64B lines.
// ---------------------------------------------------------------------------
__global__ __launch_bounds__(256) void k_diff_t(const float* __restrict__ xr,
                                                const float* __restrict__ xi,
                                                float* __restrict__ diffp,
                                                unsigned short* __restrict__ Xt) {
  __shared__ __align__(16) unsigned short ldsA[512 * 40];   // 40 KB
  __shared__ __align__(16) unsigned short ldsB[512 * 40];   // 40 KB
  int bg = blockIdx.x, hc = blockIdx.y;
  int b = bg >> 1, g = bg & 1;
  int c0 = b * NC + 2 * g, c1 = c0 + 1;
  int t = threadIdx.x;
  int q = t & 127, rg = t >> 7;
  float4v acc = {0.f, 0.f, 0.f, 0.f};

#pragma unroll
  for (int phase = 0; phase < 2; ++phase) {
    const float* PA = (phase ? xr + (size_t)c1 * NH * NW : xr + (size_t)c0 * NH * NW);
    const float* PB = (phase ? xi + (size_t)c0 * NH * NW : xi + (size_t)c1 * NH * NW);
    int icA = phase ? c1 : c0;   // real part dest channel (col base 0)
    int icB = phase ? c0 : c1;   // imag part dest channel (col base 512)
#pragma unroll
    for (int s = 0; s < 2; ++s) {          // 32-h subtile
      int hbase = hc * 64 + s * 32 + rg * 16;
      // pack phase: 2 groups of 8 h each
#pragma unroll
      for (int i8 = 0; i8 < 2; ++i8) {
        short8 pA[4], pB[4];
#pragma unroll
        for (int u = 0; u < 8; ++u) {
          int h = hbase + i8 * 8 + u;
          float4v a  = *(const float4v*)(PA + (size_t)h * NW + q * 4);
          float4v bb = *(const float4v*)(PB + (size_t)h * NW + q * 4);
#pragma unroll
          for (int k = 0; k < 4; ++k) {
            acc[k] += fabsf(fabsf(a[k]) - fabsf(bb[k]));
            pA[k][u] = (short)f2bf(a[k]);
            pB[k][u] = (short)f2bf(bb[k]);
          }
        }
        int ch = rg * 2 + i8;              // 16B chunk index within 32 h
#pragma unroll
        for (int k = 0; k < 4; ++k) {
          int w = q * 4 + k;
          int chs = ch ^ ((w >> 2) & 3);   // conflict swizzle
          *(short8*)&ldsA[w * 40 + chs * 8] = pA[k];
          *(short8*)&ldsB[w * 40 + chs * 8] = pB[k];
        }
      }
      __syncthreads();
      // store-out: 512 w x 4 chunks = 2048 units of 16B per dest; 8 iters,
      // each thread handles one unit for A and the same unit for B.
#pragma unroll
      for (int it = 0; it < 8; ++it) {
        int u = it * 256 + t;
        int w = u >> 2, cch = u & 3;
        int chs = cch ^ ((w >> 2) & 3);
        short8 vA = *(const short8*)&ldsA[w * 40 + chs * 8];
        short8 vB = *(const short8*)&ldsB[w * 40 + chs * 8];
        size_t colbase = (size_t)(hc * 64 + s * 32 + cch * 8);
        *(short8*)(Xt + ((size_t)(icA * 512 + w)) * 1024 + colbase)       = vA;
        *(short8*)(Xt + ((size_t)(icB * 512 + w)) * 1024 + 512 + colbase) = vB;
      }
      __syncthreads();
    }
  }

  // reduction: alias the scratch over ldsA (last use was before the sync)
  float4v* red = (float4v*)ldsA;
  red[t] = acc;
  __syncthreads();
  if (t < 128) {
    float4v v = red[t];
    float4v u = red[t + 128];
#pragma unroll
    for (int k = 0; k < 4; ++k) v[k] += u[k];
    *(float4v*)(diffp + ((size_t)hc * 64 + bg) * NW + q * 4) = v;
  }
}

// ---------------------------------------------------------------------------
// Stage 2: sum 8 partials, T smallest per (b,g), stable-argsort rank.
// ---------------------------------------------------------------------------
__global__ void k_select(const float* __restrict__ diffp, int* __restrict__ sel) {
  __shared__ float v[NW];
  int w = threadIdx.x;
  int bg = blockIdx.x;
  float mine = 0.f;
#pragma unroll
  for (int hc = 0; hc < 8; ++hc) mine += diffp[((size_t)hc * 64 + bg) * NW + w];
  v[w] = mine;
  __syncthreads();
  int rank = 0;
  for (int u = 0; u < NW; ++u) {
    float o = v[u];
    rank += (o < mine) || (o == mine && u < w);
  }
  if (rank < NT) sel[bg * NT + rank] = w;
}

// ---------------------------------------------------------------------------
// Build A_big via LDS cos/sin LUT, short8 stores.
// ---------------------------------------------------------------------------
__global__ __launch_bounds__(256) void k_build_T(unsigned short* __restrict__ Tb) {
  __shared__ float2 lt[512];
  int t = threadIdx.x;
  {
    float s, c;
    sincosf(6.2831853071795864769f * (float)t * (1.0f / 512.0f), &s, &c);
    lt[t] = make_float2(c, s);
    sincosf(6.2831853071795864769f * (float)(t + 256) * (1.0f / 512.0f), &s, &c);
    lt[t + 256] = make_float2(c, s);
  }
  __syncthreads();
  int idx0 = (blockIdx.x * 256 + t) * 8;
  int m = idx0 >> 10, k0 = idx0 & 1023;
  int hm = m & 511, rm = m >> 9;
  int rk = k0 >> 9;                       // constant within the 8-group
  short8 o;
#pragma unroll
  for (int u = 0; u < 8; ++u) {
    int hk = (k0 + u) & 511;
    float2 cs = lt[(hm * hk) & 511];
    float val = (rm == rk) ? cs.x : (rk ? -cs.y : cs.y);
    o[u] = (short)f2bf(val * (1.0f / 512.0f));
  }
  *(short8*)(Tb + idx0) = o;
}

// ---------------------------------------------------------------------------
// Build E via LUT, short8 stores, high-occupancy grid (64 bg x 16 chunks)
// ---------------------------------------------------------------------------
__global__ __launch_bounds__(256) void k_build_E(const int* __restrict__ sel,
                                                 unsigned short* __restrict__ Eb) {
  __shared__ int wsel[NT];
  __shared__ float2 lt[512];
  int bg = blockIdx.x;
  int t = threadIdx.x;
  {
    float s, c;
    sincosf(6.2831853071795864769f * (float)t * (1.0f / 512.0f), &s, &c);
    lt[t] = make_float2(c, s);
    sincosf(6.2831853071795864769f * (float)(t + 256) * (1.0f / 512.0f), &s, &c);
    lt[t + 256] = make_float2(c, s);
  }
  if (t < NT) wsel[t] = sel[bg * NT + t];
  __syncthreads();
  int base = blockIdx.y * 8192;
#pragma unroll
  for (int i = 0; i < 4; ++i) {
    int idx0 = base + (i * 256 + t) * 8;    // group of 8 consecutive outputs
    int n = idx0 >> 7, kidx0 = idx0 & 127;
    int j0 = kidx0 & 63, half = kidx0 >> 6; // constant within group
    int part = n >> 9, kk = n & 511;
    short8 o;
#pragma unroll
    for (int u = 0; u < 8; ++u) {
      int w = wsel[j0 + u];
      float2 cs = lt[(kk * w) & 511];
      float val = part == 0 ? (half ? cs.y : cs.x) : (half ? cs.x : -cs.y);
      o[u] = (short)f2bf(val);
    }
    *(short8*)(Eb + (size_t)bg * 131072 + idx0) = o;
  }
}

// ---------------------------------------------------------------------------
// GEMM stage 3: C[1024 x 8192] = T[1024 x 1024] * Xsel^T, where B-rows are
// gathered DIRECTLY from Xt via sel (per-lane global src for gld16; pointer
// per row precomputed once). Double-buffered LDS, one barrier per K-step.
// ---------------------------------------------------------------------------
__global__ __launch_bounds__(256) void k_gemm3(const unsigned short* __restrict__ Tb,
                                               const unsigned short* __restrict__ Xt,
                                               const int* __restrict__ sel,
                                               unsigned short* __restrict__ Yg) {
  __shared__ __align__(16) unsigned short Al[2][128 * BK];
  __shared__ __align__(16) unsigned short Bl[2][128 * BK];
  // bijective chunked XCD swizzle, nwg = 512
  int lin = blockIdx.y * 64 + blockIdx.x;
  int swz = (lin & 7) * 64 + (lin >> 3);
  int n0 = (swz & 63) * 128;
  int m0 = (swz >> 6) * 128;
  int img0 = n0 >> 6;                      // two imgs: img0, img0+1, same (b,g)
  int bg = (img0 >> 2) * 2 + ((img0 >> 1) & 1);
  int tid = threadIdx.x;
  int lane = tid & 63, wid = tid >> 6;
  int wm = wid >> 1, wn = wid & 1;
  int quad = lane >> 4, l15 = lane & 15;
  int srow = lane >> 2, sqd = lane & 3;

  // per-lane source pointers for the two staging chunks (fixed across K)
  const unsigned short* srcA[2];
  const unsigned short* srcB[2];
#pragma unroll
  for (int p = 0; p < 2; ++p) {
    int chunk = wid * 2 + p;
    int row = chunk * 16 + srow;
    int sq = sqd ^ ((row >> 1) & 3);
    srcA[p] = Tb + (size_t)(m0 + row) * 1024 + sq * 8;
    int imgB = img0 + (row >> 6), j = row & 63;
    int w = sel[bg * NT + j];
    srcB[p] = Xt + ((size_t)(imgB * 512 + w)) * 1024 + sq * 8;
  }

  float4v acc[4][4];
#pragma unroll
  for (int i = 0; i < 4; ++i)
#pragma unroll
    for (int j = 0; j < 4; ++j) acc[i][j] = (float4v){0.f, 0.f, 0.f, 0.f};

#define STAGE3(buf, kk0)                                          \
  {                                                               \
    _Pragma("unroll")                                             \
    for (int p = 0; p < 2; ++p) {                                 \
      int chunk = wid * 2 + p;                                    \
      gld16(srcA[p] + (kk0), &Al[buf][chunk * 512]);              \
      gld16(srcB[p] + (kk0), &Bl[buf][chunk * 512]);              \
    }                                                             \
  }

  STAGE3(0, 0);
  __syncthreads();
  int cur = 0;
  for (int t = 0; t < 32; ++t) {
    if (t < 31) STAGE3(cur ^ 1, (t + 1) * 32);

    short8 af[4], bfv[4];
#pragma unroll
    for (int tt = 0; tt < 4; ++tt) {
      int ra = wm * 64 + tt * 16 + l15;
      int rb = wn * 64 + tt * 16 + l15;
      af[tt]  = *(const short8*)&Al[cur][ra * BK + ((quad ^ ((ra >> 1) & 3)) << 3)];
      bfv[tt] = *(const short8*)&Bl[cur][rb * BK + ((quad ^ ((rb >> 1) & 3)) << 3)];
    }
#pragma unroll
    for (int tm = 0; tm < 4; ++tm)
#pragma unroll
      for (int tn = 0; tn < 4; ++tn)
        acc[tm][tn] = __builtin_amdgcn_mfma_f32_16x16x32_bf16(af[tm], bfv[tn], acc[tm][tn], 0, 0, 0);

    __syncthreads();
    cur ^= 1;
  }

  // epilogue: C[m,n] -> Yg[(n>>6)][m&511][(m>>9)*64 + (n&63)]
#pragma unroll
  for (int tm = 0; tm < 4; ++tm)
#pragma unroll
    for (int tn = 0; tn < 4; ++tn)
#pragma unroll
      for (int r = 0; r < 4; ++r) {
        int m = m0 + wm * 64 + tm * 16 + quad * 4 + r;
        int n = n0 + wn * 64 + tn * 16 + l15;
        int img = n >> 6, j = n & 63;
        int h = m & 511, ri = m >> 9;
        Yg[((size_t)img * 512 + h) * 128 + ri * 64 + j] = f2bf(acc[tm][tn][r]);
      }
}

// ---------------------------------------------------------------------------
// GEMM stage 4 (batched over bg): whole-K (128) single-stage LDS panel,
// one barrier pair, 64 MFMA/wave unbroken. Chunk-XOR swizzle both sides.
// ---------------------------------------------------------------------------
__global__ __launch_bounds__(256) void k_gemm4(const unsigned short* __restrict__ Yg,
                                               const unsigned short* __restrict__ Eball,
                                               float2* __restrict__ out) {
  __shared__ __align__(16) unsigned short Al[128 * 128];
  __shared__ __align__(16) unsigned short Bl[128 * 128];
  // bijective chunked XCD swizzle, nwg = 4096 -> 8 bg per XCD
  int lin = blockIdx.x + blockIdx.y * 8 + blockIdx.z * 64;
  int swz = (lin & 7) * 512 + (lin >> 3);
  int n0 = (swz & 7) * 64;           // kk base (64 kk -> 128 cols)
  int m0 = ((swz >> 3) & 7) * 128;
  int bg = swz >> 6;
  int b = bg >> 1, g = bg & 1;
  int img0 = b * 4 + 2 * g;
  const unsigned short* Ab = Yg + (size_t)img0 * 512 * 128;
  const unsigned short* Eb = Eball + (size_t)bg * 131072;

  int tid = threadIdx.x;
  int lane = tid & 63, wid = tid >> 6;
  int wm = wid >> 1, wn = wid & 1;
  int quad = lane >> 4, l15 = lane & 15;
  int lrow4 = lane >> 4, cch = lane & 15;

  // stage whole 128x128 panels: 32 gld16 calls each, 8 per wave
#pragma unroll
  for (int c8 = 0; c8 < 8; ++c8) {
    int call = wid * 8 + c8;            // 0..31, wave-uniform
    int row = call * 4 + lrow4;         // LDS row this lane feeds
    int sch = cch ^ (row & 7);          // inverse swizzle on global src
    gld16(&Ab[(size_t)(m0 + row) * 128 + sch * 8], &Al[call * 512]);
    int l = row & 63, wnB = row >> 6;
    int part = l >> 5;
    int grow = part * 512 + n0 + wnB * 32 + (l & 31);
    gld16(&Eb[(size_t)grow * 128 + sch * 8], &Bl[call * 512]);
  }
  __syncthreads();

  float4v acc[4][4];
#pragma unroll
  for (int i = 0; i < 4; ++i)
#pragma unroll
    for (int j = 0; j < 4; ++j) acc[i][j] = (float4v){0.f, 0.f, 0.f, 0.f};

#pragma unroll
  for (int ks = 0; ks < 4; ++ks) {
    short8 af[4], bfv[4];
#pragma unroll
    for (int tt = 0; tt < 4; ++tt) {
      int ra = wm * 64 + tt * 16 + l15;
      int rb = wn * 64 + tt * 16 + l15;
      af[tt]  = *(const short8*)&Al[ra * 128 + (((ks * 4 + quad) ^ (ra & 7)) << 3)];
      bfv[tt] = *(const short8*)&Bl[rb * 128 + (((ks * 4 + quad) ^ (rb & 7)) << 3)];
    }
#pragma unroll
    for (int tm = 0; tm < 4; ++tm)
#pragma unroll
      for (int tn = 0; tn < 4; ++tn)
        acc[tm][tn] = __builtin_amdgcn_mfma_f32_16x16x32_bf16(af[tm], bfv[tn], acc[tm][tn], 0, 0, 0);
  }

  // epilogue: pair real (t2) with imag (t2+2) -> float2 store
#pragma unroll
  for (int tm = 0; tm < 4; ++tm)
#pragma unroll
    for (int t2 = 0; t2 < 2; ++t2)
#pragma unroll
      for (int r = 0; r < 4; ++r) {
        int m = m0 + wm * 64 + tm * 16 + quad * 4 + r;
        int ch = m >> 9, h = m & 511;
        int img = img0 + ch;
        int kk = n0 + wn * 32 + t2 * 16 + l15;
        float2 v = make_float2(acc[tm][t2][r] + 0.5f, acc[tm][t2 + 2][r]);
        out[((size_t)(img * 512 + h)) * 512 + kk] = v;
      }
}

extern "C" void kernel_launch(void* const* d_in, const int* in_sizes, int n_in,
                              void* d_out, int out_size, void* d_ws, size_t ws_size,
                              hipStream_t stream) {
  const float* xr = (const float*)d_in[0];
  const float* xi = (const float*)d_in[1];
  float2* out = (float2*)d_out;

  char* ws = (char*)d_ws;
  float*          diffp = (float*)ws;                          // 1 MB
  int*            sel   = (int*)(ws + 1048576);                // 16 KB
  unsigned short* Tb    = (unsigned short*)(ws + 2097152);     // 2 MB
  unsigned short* Eb    = (unsigned short*)(ws + 4194304);     // 16 MB
  unsigned short* Yg    = (unsigned short*)(ws + 20971520);    // 16 MB
  unsigned short* Xt    = (unsigned short*)(ws + 37748736);    // 128 MB

  k_diff_t <<<dim3(NB * NG, 8), 256, 0, stream>>>(xr, xi, diffp, Xt);
  k_select <<<NB * NG,          NW, 0, stream>>>(diffp, sel);
  k_build_T<<<512,              256, 0, stream>>>(Tb);
  k_build_E<<<dim3(NB * NG, 16),256, 0, stream>>>(sel, Eb);
  k_gemm3  <<<dim3(64, 8),      256, 0, stream>>>(Tb, Xt, sel, Yg);
  k_gemm4  <<<dim3(8, 8, 64),   256, 0, stream>>>(Yg, Eb, out);
}

// Round 6
// 562.006 us; speedup vs baseline: 1.1508x; 1.0178x over previous
//
#include <hip/hip_runtime.h>
#include <math.h>

#define NB 32
#define NC 4
#define NH 512
#define NW 512
#define NT 64
#define NG 2
#define BK 32

typedef __attribute__((ext_vector_type(8))) short short8;
typedef __attribute__((ext_vector_type(4))) float float4v;

__device__ inline unsigned short f2bf(float f) {
  union { float f; unsigned u; } v; v.f = f;
  unsigned r = v.u + 0x7FFF + ((v.u >> 16) & 1);
  return (unsigned short)(r >> 16);
}

// async global->LDS, 16B per lane; dst is wave-uniform base, HW adds lane*16.
// global src IS per-lane.
__device__ __forceinline__ void gld16(const unsigned short* g, unsigned short* l) {
  __builtin_amdgcn_global_load_lds(
      (__attribute__((address_space(1))) const unsigned int*)g,
      (__attribute__((address_space(3))) unsigned int*)l, 16, 0, 0);
}

// ---------------------------------------------------------------------------
// Dispatch 1 (merged): blocks [0,512) = diff partials + LDS-routed transpose
// (unchanged from R5); blocks [512,1024) = build T matrix via LUT (unchanged).
// ---------------------------------------------------------------------------
__global__ __launch_bounds__(256) void k_diff_T(const float* __restrict__ xr,
                                                const float* __restrict__ xi,
                                                float* __restrict__ diffp,
                                                unsigned short* __restrict__ Xt,
                                                unsigned short* __restrict__ Tb) {
  __shared__ __align__(16) unsigned short ldsA[512 * 40];   // 40 KB
  __shared__ __align__(16) unsigned short ldsB[512 * 40];   // 40 KB
  int lin = blockIdx.x;
  int t = threadIdx.x;

  if (lin >= 512) {
    // ---- build_T branch (uses first 4KB of ldsA as the cos/sin LUT) ----
    float2* lt = (float2*)ldsA;
    {
      float s, c;
      sincosf(6.2831853071795864769f * (float)t * (1.0f / 512.0f), &s, &c);
      lt[t] = make_float2(c, s);
      sincosf(6.2831853071795864769f * (float)(t + 256) * (1.0f / 512.0f), &s, &c);
      lt[t + 256] = make_float2(c, s);
    }
    __syncthreads();
    int idx0 = ((lin - 512) * 256 + t) * 8;
    int m = idx0 >> 10, k0 = idx0 & 1023;
    int hm = m & 511, rm = m >> 9;
    int rk = k0 >> 9;                       // constant within the 8-group
    short8 o;
#pragma unroll
    for (int u = 0; u < 8; ++u) {
      int hk = (k0 + u) & 511;
      float2 cs = lt[(hm * hk) & 511];
      float val = (rm == rk) ? cs.x : (rk ? -cs.y : cs.y);
      o[u] = (short)f2bf(val * (1.0f / 512.0f));
    }
    *(short8*)(Tb + idx0) = o;
    return;
  }

  // ---- diff + transpose branch ----
  int bg = lin & 63, hc = lin >> 6;
  int b = bg >> 1, g = bg & 1;
  int c0 = b * NC + 2 * g, c1 = c0 + 1;
  int q = t & 127, rg = t >> 7;
  float4v acc = {0.f, 0.f, 0.f, 0.f};

#pragma unroll
  for (int phase = 0; phase < 2; ++phase) {
    const float* PA = (phase ? xr + (size_t)c1 * NH * NW : xr + (size_t)c0 * NH * NW);
    const float* PB = (phase ? xi + (size_t)c0 * NH * NW : xi + (size_t)c1 * NH * NW);
    int icA = phase ? c1 : c0;   // real part dest channel (col base 0)
    int icB = phase ? c0 : c1;   // imag part dest channel (col base 512)
#pragma unroll
    for (int s = 0; s < 2; ++s) {          // 32-h subtile
      int hbase = hc * 64 + s * 32 + rg * 16;
#pragma unroll
      for (int i8 = 0; i8 < 2; ++i8) {
        short8 pA[4], pB[4];
#pragma unroll
        for (int u = 0; u < 8; ++u) {
          int h = hbase + i8 * 8 + u;
          float4v a  = *(const float4v*)(PA + (size_t)h * NW + q * 4);
          float4v bb = *(const float4v*)(PB + (size_t)h * NW + q * 4);
#pragma unroll
          for (int k = 0; k < 4; ++k) {
            acc[k] += fabsf(fabsf(a[k]) - fabsf(bb[k]));
            pA[k][u] = (short)f2bf(a[k]);
            pB[k][u] = (short)f2bf(bb[k]);
          }
        }
        int ch = rg * 2 + i8;              // 16B chunk index within 32 h
#pragma unroll
        for (int k = 0; k < 4; ++k) {
          int w = q * 4 + k;
          int chs = ch ^ ((w >> 2) & 3);   // conflict swizzle
          *(short8*)&ldsA[w * 40 + chs * 8] = pA[k];
          *(short8*)&ldsB[w * 40 + chs * 8] = pB[k];
        }
      }
      __syncthreads();
#pragma unroll
      for (int it = 0; it < 8; ++it) {
        int u = it * 256 + t;
        int w = u >> 2, cch = u & 3;
        int chs = cch ^ ((w >> 2) & 3);
        short8 vA = *(const short8*)&ldsA[w * 40 + chs * 8];
        short8 vB = *(const short8*)&ldsB[w * 40 + chs * 8];
        size_t colbase = (size_t)(hc * 64 + s * 32 + cch * 8);
        *(short8*)(Xt + ((size_t)(icA * 512 + w)) * 1024 + colbase)       = vA;
        *(short8*)(Xt + ((size_t)(icB * 512 + w)) * 1024 + 512 + colbase) = vB;
      }
      __syncthreads();
    }
  }

  // reduction: alias the scratch over ldsA (guarded by the sync above)
  float4v* red = (float4v*)ldsA;
  red[t] = acc;
  __syncthreads();
  if (t < 128) {
    float4v v = red[t];
    float4v u = red[t + 128];
#pragma unroll
    for (int k = 0; k < 4; ++k) v[k] += u[k];
    *(float4v*)(diffp + ((size_t)hc * 64 + bg) * NW + q * 4) = v;
  }
}

// ---------------------------------------------------------------------------
// Dispatch 2: sum 8 partials, T smallest per (b,g), stable-argsort rank.
// ---------------------------------------------------------------------------
__global__ void k_select(const float* __restrict__ diffp, int* __restrict__ sel) {
  __shared__ float v[NW];
  int w = threadIdx.x;
  int bg = blockIdx.x;
  float mine = 0.f;
#pragma unroll
  for (int hc = 0; hc < 8; ++hc) mine += diffp[((size_t)hc * 64 + bg) * NW + w];
  v[w] = mine;
  __syncthreads();
  int rank = 0;
  for (int u = 0; u < NW; ++u) {
    float o = v[u];
    rank += (o < mine) || (o == mine && u < w);
  }
  if (rank < NT) sel[bg * NT + rank] = w;
}

// ---------------------------------------------------------------------------
// Dispatch 3 (merged): blocks [0,512) = GEMM stage 3 (unchanged: B-rows
// gathered directly from Xt via sel, double-buffered LDS, gld16, XOR-quad
// swizzle, XCD swizzle); blocks [512,576) = build_E, one block per bg.
// ---------------------------------------------------------------------------
__global__ __launch_bounds__(256) void k_gemm3E(const unsigned short* __restrict__ Tb,
                                                const unsigned short* __restrict__ Xt,
                                                const int* __restrict__ sel,
                                                unsigned short* __restrict__ Yg,
                                                unsigned short* __restrict__ Eb) {
  __shared__ __align__(16) unsigned short Al[2][128 * BK];
  __shared__ __align__(16) unsigned short Bl[2][128 * BK];
  __shared__ float2 ltE[512];
  __shared__ int wselE[NT];
  int lin = blockIdx.x;
  int tid = threadIdx.x;

  if (lin >= 512) {
    // ---- build_E branch: one block per bg, 512 values/thread ----
    int bg = lin - 512;
    {
      float s, c;
      sincosf(6.2831853071795864769f * (float)tid * (1.0f / 512.0f), &s, &c);
      ltE[tid] = make_float2(c, s);
      sincosf(6.2831853071795864769f * (float)(tid + 256) * (1.0f / 512.0f), &s, &c);
      ltE[tid + 256] = make_float2(c, s);
    }
    if (tid < NT) wselE[tid] = sel[bg * NT + tid];
    __syncthreads();
    for (int i = 0; i < 64; ++i) {
      int idx0 = (i * 256 + tid) * 8;         // 0 .. 131071 in groups of 8
      int n = idx0 >> 7, kidx0 = idx0 & 127;
      int j0 = kidx0 & 63, half = kidx0 >> 6; // constant within group
      int part = n >> 9, kk = n & 511;
      short8 o;
#pragma unroll
      for (int u = 0; u < 8; ++u) {
        int w = wselE[j0 + u];
        float2 cs = ltE[(kk * w) & 511];
        float val = part == 0 ? (half ? cs.y : cs.x) : (half ? cs.x : -cs.y);
        o[u] = (short)f2bf(val);
      }
      *(short8*)(Eb + (size_t)bg * 131072 + idx0) = o;
    }
    return;
  }

  // ---- gemm3 branch ----
  // bijective chunked XCD swizzle over the 512 gemm blocks
  int swz = (lin & 7) * 64 + (lin >> 3);
  int n0 = (swz & 63) * 128;
  int m0 = (swz >> 6) * 128;
  int img0 = n0 >> 6;                      // two imgs: img0, img0+1, same (b,g)
  int bg = (img0 >> 2) * 2 + ((img0 >> 1) & 1);
  int lane = tid & 63, wid = tid >> 6;
  int wm = wid >> 1, wn = wid & 1;
  int quad = lane >> 4, l15 = lane & 15;
  int srow = lane >> 2, sqd = lane & 3;

  // per-lane source pointers for the two staging chunks (fixed across K)
  const unsigned short* srcA[2];
  const unsigned short* srcB[2];
#pragma unroll
  for (int p = 0; p < 2; ++p) {
    int chunk = wid * 2 + p;
    int row = chunk * 16 + srow;
    int sq = sqd ^ ((row >> 1) & 3);
    srcA[p] = Tb + (size_t)(m0 + row) * 1024 + sq * 8;
    int imgB = img0 + (row >> 6), j = row & 63;
    int w = sel[bg * NT + j];
    srcB[p] = Xt + ((size_t)(imgB * 512 + w)) * 1024 + sq * 8;
  }

  float4v acc[4][4];
#pragma unroll
  for (int i = 0; i < 4; ++i)
#pragma unroll
    for (int j = 0; j < 4; ++j) acc[i][j] = (float4v){0.f, 0.f, 0.f, 0.f};

#define STAGE3(buf, kk0)                                          \
  {                                                               \
    _Pragma("unroll")                                             \
    for (int p = 0; p < 2; ++p) {                                 \
      int chunk = wid * 2 + p;                                    \
      gld16(srcA[p] + (kk0), &Al[buf][chunk * 512]);              \
      gld16(srcB[p] + (kk0), &Bl[buf][chunk * 512]);              \
    }                                                             \
  }

  STAGE3(0, 0);
  __syncthreads();
  int cur = 0;
  for (int t = 0; t < 32; ++t) {
    if (t < 31) STAGE3(cur ^ 1, (t + 1) * 32);

    short8 af[4], bfv[4];
#pragma unroll
    for (int tt = 0; tt < 4; ++tt) {
      int ra = wm * 64 + tt * 16 + l15;
      int rb = wn * 64 + tt * 16 + l15;
      af[tt]  = *(const short8*)&Al[cur][ra * BK + ((quad ^ ((ra >> 1) & 3)) << 3)];
      bfv[tt] = *(const short8*)&Bl[cur][rb * BK + ((quad ^ ((rb >> 1) & 3)) << 3)];
    }
#pragma unroll
    for (int tm = 0; tm < 4; ++tm)
#pragma unroll
      for (int tn = 0; tn < 4; ++tn)
        acc[tm][tn] = __builtin_amdgcn_mfma_f32_16x16x32_bf16(af[tm], bfv[tn], acc[tm][tn], 0, 0, 0);

    __syncthreads();
    cur ^= 1;
  }

  // epilogue: C[m,n] -> Yg[(n>>6)][m&511][(m>>9)*64 + (n&63)]
#pragma unroll
  for (int tm = 0; tm < 4; ++tm)
#pragma unroll
    for (int tn = 0; tn < 4; ++tn)
#pragma unroll
      for (int r = 0; r < 4; ++r) {
        int m = m0 + wm * 64 + tm * 16 + quad * 4 + r;
        int n = n0 + wn * 64 + tn * 16 + l15;
        int img = n >> 6, j = n & 63;
        int h = m & 511, ri = m >> 9;
        Yg[((size_t)img * 512 + h) * 128 + ri * 64 + j] = f2bf(acc[tm][tn][r]);
      }
}

// ---------------------------------------------------------------------------
// Dispatch 4: GEMM stage 4 (batched over bg): whole-K (128) single-stage LDS
// panel, one barrier pair, 64 MFMA/wave unbroken. Chunk-XOR swizzle.
// ---------------------------------------------------------------------------
__global__ __launch_bounds__(256) void k_gemm4(const unsigned short* __restrict__ Yg,
                                               const unsigned short* __restrict__ Eball,
                                               float2* __restrict__ out) {
  __shared__ __align__(16) unsigned short Al[128 * 128];
  __shared__ __align__(16) unsigned short Bl[128 * 128];
  // bijective chunked XCD swizzle, nwg = 4096 -> 8 bg per XCD
  int lin = blockIdx.x + blockIdx.y * 8 + blockIdx.z * 64;
  int swz = (lin & 7) * 512 + (lin >> 3);
  int n0 = (swz & 7) * 64;           // kk base (64 kk -> 128 cols)
  int m0 = ((swz >> 3) & 7) * 128;
  int bg = swz >> 6;
  int b = bg >> 1, g = bg & 1;
  int img0 = b * 4 + 2 * g;
  const unsigned short* Ab = Yg + (size_t)img0 * 512 * 128;
  const unsigned short* Eb = Eball + (size_t)bg * 131072;

  int tid = threadIdx.x;
  int lane = tid & 63, wid = tid >> 6;
  int wm = wid >> 1, wn = wid & 1;
  int quad = lane >> 4, l15 = lane & 15;
  int lrow4 = lane >> 4, cch = lane & 15;

  // stage whole 128x128 panels: 32 gld16 calls each, 8 per wave
#pragma unroll
  for (int c8 = 0; c8 < 8; ++c8) {
    int call = wid * 8 + c8;            // 0..31, wave-uniform
    int row = call * 4 + lrow4;         // LDS row this lane feeds
    int sch = cch ^ (row & 7);          // inverse swizzle on global src
    gld16(&Ab[(size_t)(m0 + row) * 128 + sch * 8], &Al[call * 512]);
    int l = row & 63, wnB = row >> 6;
    int part = l >> 5;
    int grow = part * 512 + n0 + wnB * 32 + (l & 31);
    gld16(&Eb[(size_t)grow * 128 + sch * 8], &Bl[call * 512]);
  }
  __syncthreads();

  float4v acc[4][4];
#pragma unroll
  for (int i = 0; i < 4; ++i)
#pragma unroll
    for (int j = 0; j < 4; ++j) acc[i][j] = (float4v){0.f, 0.f, 0.f, 0.f};

#pragma unroll
  for (int ks = 0; ks < 4; ++ks) {
    short8 af[4], bfv[4];
#pragma unroll
    for (int tt = 0; tt < 4; ++tt) {
      int ra = wm * 64 + tt * 16 + l15;
      int rb = wn * 64 + tt * 16 + l15;
      af[tt]  = *(const short8*)&Al[ra * 128 + (((ks * 4 + quad) ^ (ra & 7)) << 3)];
      bfv[tt] = *(const short8*)&Bl[rb * 128 + (((ks * 4 + quad) ^ (rb & 7)) << 3)];
    }
#pragma unroll
    for (int tm = 0; tm < 4; ++tm)
#pragma unroll
      for (int tn = 0; tn < 4; ++tn)
        acc[tm][tn] = __builtin_amdgcn_mfma_f32_16x16x32_bf16(af[tm], bfv[tn], acc[tm][tn], 0, 0, 0);
  }

  // epilogue: pair real (t2) with imag (t2+2) -> float2 store
#pragma unroll
  for (int tm = 0; tm < 4; ++tm)
#pragma unroll
    for (int t2 = 0; t2 < 2; ++t2)
#pragma unroll
      for (int r = 0; r < 4; ++r) {
        int m = m0 + wm * 64 + tm * 16 + quad * 4 + r;
        int ch = m >> 9, h = m & 511;
        int img = img0 + ch;
        int kk = n0 + wn * 32 + t2 * 16 + l15;
        float2 v = make_float2(acc[tm][t2][r] + 0.5f, acc[tm][t2 + 2][r]);
        out[((size_t)(img * 512 + h)) * 512 + kk] = v;
      }
}

extern "C" void kernel_launch(void* const* d_in, const int* in_sizes, int n_in,
                              void* d_out, int out_size, void* d_ws, size_t ws_size,
                              hipStream_t stream) {
  const float* xr = (const float*)d_in[0];
  const float* xi = (const float*)d_in[1];
  float2* out = (float2*)d_out;

  char* ws = (char*)d_ws;
  float*          diffp = (float*)ws;                          // 1 MB
  int*            sel   = (int*)(ws + 1048576);                // 16 KB
  unsigned short* Tb    = (unsigned short*)(ws + 2097152);     // 2 MB
  unsigned short* Eb    = (unsigned short*)(ws + 4194304);     // 16 MB
  unsigned short* Yg    = (unsigned short*)(ws + 20971520);    // 16 MB
  unsigned short* Xt    = (unsigned short*)(ws + 37748736);    // 128 MB

  k_diff_T <<<1024,           256, 0, stream>>>(xr, xi, diffp, Xt, Tb);
  k_select <<<NB * NG,        NW,  0, stream>>>(diffp, sel);
  k_gemm3E <<<576,            256, 0, stream>>>(Tb, Xt, sel, Yg, Eb);
  k_gemm4  <<<dim3(8, 8, 64), 256, 0, stream>>>(Yg, Eb, out);
}